// Round 1
// baseline (275.175 us; speedup 1.0000x reference)
//
#include <hip/hip_runtime.h>
#include <hip/hip_bf16.h>
#include <stdint.h>

#define BB 2
#define SS 2048
#define DDIM 1024
#define HH 16
#define DEPTH 64
#define MROWS (BB*SS)   // 4096

typedef short bf16x8 __attribute__((ext_vector_type(8)));
typedef float f32x4 __attribute__((ext_vector_type(4)));

__device__ inline ushort f2bf(float f) {
  union { float f; unsigned u; } v; v.f = f;
  unsigned r = v.u + 0x7fffu + ((v.u >> 16) & 1u);
  return (ushort)(r >> 16);
}

__device__ inline void gload_lds16(const void* g, void* l) {
  __builtin_amdgcn_global_load_lds(
      (const __attribute__((address_space(1))) unsigned*)g,
      (__attribute__((address_space(3))) unsigned*)l,
      16, 0, 0);
}

// ---------------- fp32 -> bf16 convert (vectorized) ----------------
__global__ void cvt_f32_bf16_kernel(const float* __restrict__ in,
                                    ushort* __restrict__ out, int n8) {
  int i = blockIdx.x * blockDim.x + threadIdx.x;
  if (i >= n8) return;
  const float4* p = (const float4*)in + (size_t)i * 2;
  float4 a = p[0], b = p[1];
  ushort tmp[8] = { f2bf(a.x), f2bf(a.y), f2bf(a.z), f2bf(a.w),
                    f2bf(b.x), f2bf(b.y), f2bf(b.z), f2bf(b.w) };
  *(uint4*)(out + (size_t)i * 8) = *(uint4*)tmp;
}

// ---------------- weight transpose + convert: T[n][k] = W[k][n] ----------------
__global__ void wtrans_kernel(const float* __restrict__ W0, const float* __restrict__ W1,
                              const float* __restrict__ W2, const float* __restrict__ W3,
                              ushort* __restrict__ T0, ushort* __restrict__ T1,
                              ushort* __restrict__ T2, ushort* __restrict__ T3) {
  __shared__ float tile[32][33];
  int z = blockIdx.z;
  const float* W = (z == 0) ? W0 : (z == 1) ? W1 : (z == 2) ? W2 : W3;
  ushort* T = (z == 0) ? T0 : (z == 1) ? T1 : (z == 2) ? T2 : T3;
  int tx = threadIdx.x, ty = threadIdx.y;   // 32 x 8
  int n0 = blockIdx.x * 32, k0 = blockIdx.y * 32;
#pragma unroll
  for (int i = 0; i < 4; i++)
    tile[ty + i * 8][tx] = W[(size_t)(k0 + ty + i * 8) * DDIM + n0 + tx];
  __syncthreads();
#pragma unroll
  for (int i = 0; i < 4; i++)
    T[(size_t)(n0 + ty + i * 8) * DDIM + k0 + tx] = f2bf(tile[tx][ty + i * 8]);
}

// ---------------- m97-structure bf16 GEMM: out = A[M][K] * Bt[N][K]^T + bias ----------------
template <bool OUT_F32>
__global__ __launch_bounds__(256) void gemm_bt_kernel(
    const ushort* __restrict__ A, const ushort* __restrict__ Bt,
    const float* __restrict__ bias, void* __restrict__ out,
    int M, int N, int K) {
  __shared__ ushort As[128 * 32];
  __shared__ ushort Bs[128 * 32];
  const int tid = threadIdx.x;
  const int w = tid >> 6, lane = tid & 63;
  const int m0 = blockIdx.y * 128, n0 = blockIdx.x * 128;
  const int wr = (w >> 1) * 64, wc = (w & 1) * 64;
  const int l4 = lane >> 4, l15 = lane & 15;
  const int srow = lane >> 2;         // 0..15
  const int scol = (lane & 3) * 8;    // bf16 elements (16B)

  f32x4 zero = {0.f, 0.f, 0.f, 0.f};
  f32x4 acc[4][4];
#pragma unroll
  for (int i = 0; i < 4; i++)
#pragma unroll
    for (int j = 0; j < 4; j++) acc[i][j] = zero;

  for (int k0 = 0; k0 < K; k0 += 32) {
#pragma unroll
    for (int it = 0; it < 2; ++it) {
      int r = it * 64 + w * 16;
      gload_lds16(A + (size_t)(m0 + r + srow) * K + k0 + scol, &As[r * 32]);
      gload_lds16(Bt + (size_t)(n0 + r + srow) * K + k0 + scol, &Bs[r * 32]);
    }
    __syncthreads();
    bf16x8 af[4], bf[4];
#pragma unroll
    for (int m = 0; m < 4; m++)
      af[m] = *(const bf16x8*)&As[(wr + m * 16 + l15) * 32 + l4 * 8];
#pragma unroll
    for (int n = 0; n < 4; n++)
      bf[n] = *(const bf16x8*)&Bs[(wc + n * 16 + l15) * 32 + l4 * 8];
#pragma unroll
    for (int m = 0; m < 4; m++)
#pragma unroll
      for (int n = 0; n < 4; n++)
        acc[m][n] = __builtin_amdgcn_mfma_f32_16x16x32_bf16(af[m], bf[n], acc[m][n], 0, 0, 0);
    __syncthreads();
  }

#pragma unroll
  for (int m = 0; m < 4; m++) {
#pragma unroll
    for (int n = 0; n < 4; n++) {
      int col = n0 + wc + n * 16 + l15;
      float bv = bias[col];
#pragma unroll
      for (int r = 0; r < 4; r++) {
        int row = m0 + wr + m * 16 + l4 * 4 + r;
        float v = acc[m][n][r] + bv;
        if (OUT_F32) ((float*)out)[(size_t)row * N + col] = v;
        else         ((ushort*)out)[(size_t)row * N + col] = f2bf(v);
      }
    }
  }
}

// ---------------- causal flash attention (bf16 MFMA, fp32 softmax) ----------------
__global__ __launch_bounds__(256) void attn_kernel(
    const ushort* __restrict__ Q, const ushort* __restrict__ K,
    const ushort* __restrict__ V, ushort* __restrict__ ctx) {
  __shared__ ushort Ks[64 * 64];        // [kv][depth]
  __shared__ ushort Vt[64 * 64];        // [depth][kv]
  __shared__ ushort Ps[4 * 16 * 64];    // per-wave [q16][kv64]
  const int tid = threadIdx.x;
  const int w = tid >> 6, lane = tid & 63;
  const int l4 = lane >> 4, l15 = lane & 15;
  const int qt = blockIdx.x, bh = blockIdx.y;
  const int b = bh >> 4, h = bh & 15;
  const size_t rowbase = (size_t)b * SS;
  const int hoff = h * DEPTH;
  const int q0 = qt * 64 + w * 16;

  bf16x8 aq[2];
#pragma unroll
  for (int c = 0; c < 2; c++)
    aq[c] = *(const bf16x8*)&Q[(rowbase + q0 + l15) * DDIM + hoff + c * 32 + l4 * 8];

  f32x4 zero = {0.f, 0.f, 0.f, 0.f};
  f32x4 o[4];
  float m_run[4], l_run[4];
#pragma unroll
  for (int d = 0; d < 4; d++) o[d] = zero;
#pragma unroll
  for (int r = 0; r < 4; r++) { m_run[r] = -__builtin_inff(); l_run[r] = 0.f; }

  const int srow = lane >> 3;        // 0..7
  const int scol = (lane & 7) * 8;   // elements
  const int ntiles = qt + 1;

  for (int t = 0; t < ntiles; ++t) {
    const int kv0 = t * 64;
    // stage K tile (linear, global_load_lds)
#pragma unroll
    for (int it = 0; it < 2; ++it) {
      int r = it * 32 + w * 8;
      gload_lds16(&K[(rowbase + kv0 + r + srow) * DDIM + hoff + scol], &Ks[r * DEPTH]);
    }
    // stage V transposed via registers
    {
      int r = tid >> 2;
      int g = (tid & 3) * 16;
      const ushort* vsrc = &V[(rowbase + kv0 + r) * DDIM + hoff + g];
      ushort tmp[16];
      *(uint4*)tmp       = *(const uint4*)vsrc;
      *(uint4*)(tmp + 8) = *(const uint4*)(vsrc + 8);
#pragma unroll
      for (int i = 0; i < 16; i++) Vt[(g + i) * 64 + r] = tmp[i];
    }
    __syncthreads();

    // S = (Q K^T) * 1/sqrt(64)
    f32x4 s[4];
#pragma unroll
    for (int n = 0; n < 4; n++) {
      f32x4 z = zero;
#pragma unroll
      for (int c = 0; c < 2; c++) {
        bf16x8 bk = *(const bf16x8*)&Ks[(n * 16 + l15) * DEPTH + c * 32 + l4 * 8];
        z = __builtin_amdgcn_mfma_f32_16x16x32_bf16(aq[c], bk, z, 0, 0, 0);
      }
      s[n] = z * 0.125f;
    }

    // causal mask + online softmax
    float rmax[4];
#pragma unroll
    for (int r = 0; r < 4; r++) {
      int qg = q0 + l4 * 4 + r;
#pragma unroll
      for (int n = 0; n < 4; n++) {
        int kg = kv0 + n * 16 + l15;
        if (kg > qg) s[n][r] = -1e9f;
      }
      float mx = fmaxf(fmaxf(s[0][r], s[1][r]), fmaxf(s[2][r], s[3][r]));
#pragma unroll
      for (int off = 1; off < 16; off <<= 1)
        mx = fmaxf(mx, __shfl_xor(mx, off));
      rmax[r] = mx;
    }
#pragma unroll
    for (int r = 0; r < 4; r++) {
      float mn = fmaxf(m_run[r], rmax[r]);
      float alpha = __expf(m_run[r] - mn);
      m_run[r] = mn;
      float rs = 0.f;
#pragma unroll
      for (int n = 0; n < 4; n++) {
        float p0 = __expf(s[n][r] - mn);
        s[n][r] = p0;
        rs += p0;
      }
      l_run[r] = l_run[r] * alpha + rs;
#pragma unroll
      for (int d = 0; d < 4; d++) o[d][r] *= alpha;
    }

    // P -> LDS (per-wave), transpose to A-fragment layout
    ushort* Pw = &Ps[w * 16 * 64];
#pragma unroll
    for (int r = 0; r < 4; r++)
#pragma unroll
      for (int n = 0; n < 4; n++)
        Pw[(l4 * 4 + r) * 64 + n * 16 + l15] = f2bf(s[n][r]);
    __syncthreads();

    // O += P V
    bf16x8 pa[2];
#pragma unroll
    for (int c = 0; c < 2; c++)
      pa[c] = *(const bf16x8*)&Pw[l15 * 64 + c * 32 + l4 * 8];
#pragma unroll
    for (int d = 0; d < 4; d++) {
#pragma unroll
      for (int c = 0; c < 2; c++) {
        bf16x8 bv = *(const bf16x8*)&Vt[(d * 16 + l15) * 64 + c * 32 + l4 * 8];
        o[d] = __builtin_amdgcn_mfma_f32_16x16x32_bf16(pa[c], bv, o[d], 0, 0, 0);
      }
    }
    __syncthreads();
  }

  // finalize: divide by row sum, write ctx (bf16)
#pragma unroll
  for (int r = 0; r < 4; r++) {
    float lv = l_run[r];
#pragma unroll
    for (int off = 1; off < 16; off <<= 1) lv += __shfl_xor(lv, off);
    l_run[r] = 1.f / lv;
  }
#pragma unroll
  for (int d = 0; d < 4; d++)
#pragma unroll
    for (int r = 0; r < 4; r++) {
      int row = q0 + l4 * 4 + r;
      ctx[(rowbase + row) * DDIM + hoff + d * 16 + l15] = f2bf(o[d][r] * l_run[r]);
    }
}

extern "C" void kernel_launch(void* const* d_in, const int* in_sizes, int n_in,
                              void* d_out, int out_size, void* d_ws, size_t ws_size,
                              hipStream_t stream) {
  const float* query = (const float*)d_in[0];
  const float* key_  = (const float*)d_in[1];
  const float* value = (const float*)d_in[2];
  // d_in[3] = mask (causal; computed analytically in-kernel)
  const float* Wq = (const float*)d_in[4];
  const float* Wk = (const float*)d_in[5];
  const float* Wv = (const float*)d_in[6];
  const float* Wo = (const float*)d_in[7];
  const float* bq = (const float*)d_in[8];
  const float* bk = (const float*)d_in[9];
  const float* bv = (const float*)d_in[10];
  const float* bo = (const float*)d_in[11];

  char* ws = (char*)d_ws;
  const size_t MB = 1u << 20;
  ushort* Xq  = (ushort*)(ws + 0 * MB);
  ushort* Xk  = (ushort*)(ws + 8 * MB);
  ushort* Xv  = (ushort*)(ws + 16 * MB);
  ushort* Wqt = (ushort*)(ws + 24 * MB);
  ushort* Wkt = (ushort*)(ws + 26 * MB);
  ushort* Wvt = (ushort*)(ws + 28 * MB);
  ushort* Wot = (ushort*)(ws + 30 * MB);
  ushort* Qb  = (ushort*)(ws + 32 * MB);
  ushort* Kb  = (ushort*)(ws + 40 * MB);
  ushort* Vb  = (ushort*)(ws + 48 * MB);
  ushort* Cb  = (ushort*)(ws + 56 * MB);

  const int n = MROWS * DDIM;           // 4,194,304
  const int n8 = n / 8;                 // 524,288
  cvt_f32_bf16_kernel<<<n8 / 256, 256, 0, stream>>>(query, Xq, n8);
  cvt_f32_bf16_kernel<<<n8 / 256, 256, 0, stream>>>(key_,  Xk, n8);
  cvt_f32_bf16_kernel<<<n8 / 256, 256, 0, stream>>>(value, Xv, n8);
  wtrans_kernel<<<dim3(32, 32, 4), dim3(32, 8), 0, stream>>>(
      Wq, Wk, Wv, Wo, Wqt, Wkt, Wvt, Wot);

  dim3 gg(DDIM / 128, MROWS / 128);     // (8, 32)
  gemm_bt_kernel<false><<<gg, 256, 0, stream>>>(Xq, Wqt, bq, Qb, MROWS, DDIM, DDIM);
  gemm_bt_kernel<false><<<gg, 256, 0, stream>>>(Xk, Wkt, bk, Kb, MROWS, DDIM, DDIM);
  gemm_bt_kernel<false><<<gg, 256, 0, stream>>>(Xv, Wvt, bv, Vb, MROWS, DDIM, DDIM);

  attn_kernel<<<dim3(SS / 64, BB * HH), 256, 0, stream>>>(Qb, Kb, Vb, Cb);

  gemm_bt_kernel<true><<<gg, 256, 0, stream>>>(Cb, Wot, bo, d_out, MROWS, DDIM, DDIM);
}